// Round 3
// baseline (352.500 us; speedup 1.0000x reference)
//
#include <hip/hip_runtime.h>
#include <math.h>

#define NN 768
#define SD 384
#define HH 12

#define W_L 0.57735026918962576f   /* sqrt(1/3) */
#define W_C 0.23570226039551584f   /* sqrt(2/36) */

typedef __attribute__((ext_vector_type(8))) short short8;
typedef __attribute__((ext_vector_type(4))) float floatx4;
typedef unsigned short ushort_t;
typedef unsigned int uint_t;

static __device__ __forceinline__ ushort_t f2bf(float f) {
  union { float f; uint_t u; } v; v.f = f;
  uint_t r = (v.u + 0x7FFFu + ((v.u >> 16) & 1u)) >> 16;
  return (ushort_t)r;
}

// ---------------- K1a: raw = single @ [Wqkv|Wqk|Wvp]  (768x1152x384) ----
__global__ __launch_bounds__(256) void k1a_gemm(
    const float* __restrict__ single, const float* __restrict__ Wqkv,
    const float* __restrict__ Wqk, const float* __restrict__ Wvp,
    float* __restrict__ raw)
{
  __shared__ float Al[64][17];
  __shared__ float Bl[16][68];
  const int tid = threadIdx.x;
  const int bm = blockIdx.x / 18, bn = blockIdx.x % 18;
  const int tr = tid >> 4, tc = tid & 15;

  const int bcol = bn*64 + (tid & 15)*4;
  const float* Wsrc; int wstride;
  if (bcol < 576)      { Wsrc = Wqkv + bcol;        wstride = 576; }
  else if (bcol < 864) { Wsrc = Wqk  + (bcol-576);  wstride = 288; }
  else                 { Wsrc = Wvp  + (bcol-864);  wstride = 288; }
  const int brow = tid >> 4;
  const int ar = tid >> 2, ac = (tid & 3)*4;

  float4 acc0 = {0,0,0,0}, acc1 = {0,0,0,0}, acc2 = {0,0,0,0}, acc3 = {0,0,0,0};

  for (int kc = 0; kc < 24; ++kc) {
    __syncthreads();
    *(float4*)&Al[ar][ac] = *(const float4*)(single + (size_t)(bm*64+ar)*SD + kc*16 + ac);
    *(float4*)&Bl[brow][(tid&15)*4] = *(const float4*)(Wsrc + (size_t)(kc*16+brow)*wstride);
    __syncthreads();
    #pragma unroll
    for (int kk = 0; kk < 16; ++kk) {
      float a0 = Al[tr*4+0][kk], a1 = Al[tr*4+1][kk], a2 = Al[tr*4+2][kk], a3 = Al[tr*4+3][kk];
      float4 bv = *(float4*)&Bl[kk][tc*4];
      acc0.x += a0*bv.x; acc0.y += a0*bv.y; acc0.z += a0*bv.z; acc0.w += a0*bv.w;
      acc1.x += a1*bv.x; acc1.y += a1*bv.y; acc1.z += a1*bv.z; acc1.w += a1*bv.w;
      acc2.x += a2*bv.x; acc2.y += a2*bv.y; acc2.z += a2*bv.z; acc2.w += a2*bv.w;
      acc3.x += a3*bv.x; acc3.y += a3*bv.y; acc3.z += a3*bv.z; acc3.w += a3*bv.w;
    }
  }
  float* o = raw + (size_t)(bm*64 + tr*4)*1152 + bn*64 + tc*4;
  *(float4*)(o)            = acc0;
  *(float4*)(o + 1152)     = acc1;
  *(float4*)(o + 2*1152)   = acc2;
  *(float4*)(o + 3*1152)   = acc3;
}

// ---------------- K1b: pack Q~ (f32), K~ (bf16), vv (f32) + frames ------
__global__ __launch_bounds__(256) void k1b_pack(
    const float* __restrict__ raw_g, const float* __restrict__ rot,
    const float* __restrict__ trans, const float* __restrict__ gamma,
    float* __restrict__ Qt, ushort_t* __restrict__ Ktb, float* __restrict__ vv)
{
  __shared__ float raw[4][1152];
  __shared__ float gbuf[4][16][HH][3];
  const int tid = threadIdx.x;
  const int i0 = blockIdx.x * 4;

  for (int s = tid; s < 4*288; s += 256) {
    int r = s / 288, q = s % 288;
    *(float4*)(&raw[r][q*4]) = *(const float4*)(raw_g + (size_t)(i0+r)*1152 + q*4);
  }
  __syncthreads();

  for (int s = tid; s < 4*576; s += 256) {
    int r = s / 576, cc = s % 576;
    int d = (cc % 192) / HH, h = cc % HH;
    int i = i0 + r;
    float val = raw[r][cc];
    if (cc < 192)       Qt[(size_t)i*384 + h*32 + d] = 0.25f*W_L*val;
    else if (cc < 384)  Ktb[(size_t)i*384 + h*32 + d] = f2bf(val);
    else                vv[(size_t)i*480 + h*40 + d] = val;
  }
  for (int s = tid; s < 768; s += 256) {
    int r = s / 192, rem = s % 192;
    int slot = rem / HH, h = rem % HH;
    int i = i0 + r;
    int base;
    if (slot < 4) base = 576 + slot*36;
    else if (slot < 8) base = 720 + (slot-4)*36;
    else base = 864 + (slot-8)*36;
    float x0 = raw[r][base + 0*12 + h];
    float x1 = raw[r][base + 1*12 + h];
    float x2 = raw[r][base + 2*12 + h];
    const float* R = rot + (size_t)i*9;
    const float* T = trans + (size_t)i*3;
    float g0 = R[0]*x0 + R[1]*x1 + R[2]*x2 + T[0];
    float g1 = R[3]*x0 + R[4]*x1 + R[5]*x2 + T[1];
    float g2 = R[6]*x0 + R[7]*x1 + R[8]*x2 + T[2];
    gbuf[r][slot][h][0]=g0; gbuf[r][slot][h][1]=g1; gbuf[r][slot][h][2]=g2;
    if (slot < 4) {
      float sc2 = 2.0f*W_L*(gamma[h]*W_C*0.5f);
      float* q = Qt + (size_t)i*384 + h*32 + 16 + slot*3;
      q[0]=sc2*g0; q[1]=sc2*g1; q[2]=sc2*g2;
    } else if (slot < 8) {
      ushort_t* k = Ktb + (size_t)i*384 + h*32 + 16 + (slot-4)*3;
      k[0]=f2bf(g0); k[1]=f2bf(g1); k[2]=f2bf(g2);
    } else {
      float* vp = vv + (size_t)i*480 + h*40 + 16 + (slot-8)*3;
      vp[0]=g0; vp[1]=g1; vp[2]=g2;
    }
  }
  __syncthreads();
  for (int s = tid; s < 96; s += 256) {
    int r = s / 24, rem = s % 24;
    int h = rem / 2, qk = rem % 2;
    int i = i0 + r;
    float sum = 0;
    int b0 = qk ? 4 : 0;
    for (int p = 0; p < 4; ++p)
      for (int t = 0; t < 3; ++t) { float g = gbuf[r][b0+p][h][t]; sum += g*g; }
    float sc = gamma[h]*W_C*0.5f;
    if (qk == 0) {
      float* q = Qt + (size_t)i*384 + h*32;
      q[28] = -W_L*sc; q[29] = -W_L*sc*sum; q[30] = 0.f; q[31] = 0.f;
    } else {
      ushort_t* k = Ktb + (size_t)i*384 + h*32;
      k[28] = f2bf(sum); k[29] = f2bf(1.f); k[30] = 0; k[31] = 0;
    }
  }
}

// ---------------- K2m: fused MFMA flash-IPA over pair rows --------------
__global__ __launch_bounds__(256) void k2m(
    const float* __restrict__ pair, const float* __restrict__ Wb,
    const float* __restrict__ Qt, const ushort_t* __restrict__ Ktb,
    const float* __restrict__ vv, const float* __restrict__ rot,
    const float* __restrict__ trans, float* __restrict__ C2)
{
  __shared__ ushort_t Tjz[2][32*136];   // j-major bf16 tile (pad 136)
  __shared__ ushort_t Tzj[2][128*40];   // z-major bf16 tile (pad 40)
  __shared__ ushort_t WbT[16*136];      // W_L * Wb transposed, bf16
  __shared__ ushort_t PT[16*40];        // softmaxed P^T bf16
  __shared__ float pl[12*33];           // softmaxed p f32
  __shared__ float lL[32*17];           // logits
  __shared__ float Qrow[384];
  __shared__ float smm[16], sms[16], scl[16];
  __shared__ float oacc[480];

  const int tid = threadIdx.x;
  const int i = blockIdx.x;
  const int lane = tid & 63;
  const int wv = tid >> 6;
  const int sj = tid & 31, szq = tid >> 5;       // staging: j, z-quarter(16z)
  const int co = lane & 15, gg = lane >> 4;      // fragment coords

  // ---- init ----
  for (int s = tid; s < 1536; s += 256) {
    int z = s / 12, h = s % 12;
    WbT[h*136 + z] = f2bf(W_L * Wb[s]);
  }
  for (int s = tid; s < 4*136; s += 256) WbT[(12 + s/136)*136 + (s%136)] = 0;
  for (int s = tid; s < 16*40; s += 256) PT[s] = 0;
  for (int s = tid; s < 384; s += 256) Qrow[s] = Qt[(size_t)i*384 + s];
  if (tid < 16) { smm[tid] = -1e30f; sms[tid] = 0.f; scl[tid] = 0.f; }
  __syncthreads();

  // wave-1 Q block-diag fragment (per-lane col = lane&15)
  short8 myQ; short8 z8;
  #pragma unroll
  for (int s = 0; s < 8; ++s) z8[s] = 0;
  #pragma unroll
  for (int s = 0; s < 8; ++s)
    myQ[s] = (co < 12) ? (short)f2bf(Qrow[co*32 + gg*8 + s]) : (short)0;

  const float* psrc = pair + (size_t)i*NN*128;

  float4 cur[4], nxt[4];
  {
    const float* s0 = psrc + (size_t)sj*128 + szq*16;
    cur[0] = *(const float4*)(s0);     cur[1] = *(const float4*)(s0+4);
    cur[2] = *(const float4*)(s0+8);   cur[3] = *(const float4*)(s0+12);
  }

  floatx4 accP[8];
  #pragma unroll
  for (int n = 0; n < 8; ++n) { accP[n][0]=0.f; accP[n][1]=0.f; accP[n][2]=0.f; accP[n][3]=0.f; }
  float accB[4] = {0,0,0,0};
  const int tid2 = tid - 128;
  const int c0 = (tid2 >= 0 && tid2 < 120) ? tid2*4 : 0;
  const int hB = c0 / 40;

  for (int t = 0; t <= 24; ++t) {
    const int buf = t & 1;
    if (t < 24) {
      if (t < 23) {
        const float* sn = psrc + (size_t)(t+1)*32*128 + (size_t)sj*128 + szq*16;
        nxt[0] = *(const float4*)(sn);     nxt[1] = *(const float4*)(sn+4);
        nxt[2] = *(const float4*)(sn+8);   nxt[3] = *(const float4*)(sn+12);
      }
      const float* cf = (const float*)cur;
      ushort_t bb[16];
      #pragma unroll
      for (int e = 0; e < 16; ++e) bb[e] = f2bf(cf[e]);
      short8 w0, w1;
      #pragma unroll
      for (int e = 0; e < 8; ++e) { w0[e] = (short)bb[e]; w1[e] = (short)bb[8+e]; }
      *(short8*)&Tjz[buf][sj*136 + szq*16]     = w0;
      *(short8*)&Tjz[buf][sj*136 + szq*16 + 8] = w1;
      #pragma unroll
      for (int e = 0; e < 16; ++e) Tzj[buf][(szq*16 + e)*40 + sj] = bb[e];
    }
    __syncthreads();  // A: tile staged

    // ---- M phase ----
    if (t < 24 && wv == 1) {
      #pragma unroll
      for (int Mt = 0; Mt < 2; ++Mt) {
        floatx4 D; D[0]=0.f; D[1]=0.f; D[2]=0.f; D[3]=0.f;
        const int jr = Mt*16 + co;
        #pragma unroll
        for (int kt = 0; kt < 4; ++kt) {
          short8 a = *(const short8*)&Tjz[buf][jr*136 + kt*32 + gg*8];
          short8 b = *(const short8*)&WbT[co*136 + kt*32 + gg*8];
          D = __builtin_amdgcn_mfma_f32_16x16x32_bf16(a, b, D, 0, 0, 0);
        }
        const ushort_t* kr = Ktb + (size_t)(t*32 + jr)*384;
        #pragma unroll
        for (int kt = 0; kt < 12; ++kt) {
          short8 a = *(const short8*)(kr + kt*32 + gg*8);
          short8 b = (co == kt) ? myQ : z8;
          D = __builtin_amdgcn_mfma_f32_16x16x32_bf16(a, b, D, 0, 0, 0);
        }
        #pragma unroll
        for (int r = 0; r < 4; ++r) lL[(Mt*16 + gg*4 + r)*17 + co] = D[r];
      }
    }
    if (t > 0) {
      const int pbuf = (t-1) & 1;
      if (wv == 0) {
        float s4[4];
        #pragma unroll
        for (int r = 0; r < 4; ++r) s4[r] = scl[gg*4 + r];
        short8 aP = *(const short8*)&PT[co*40 + gg*8];
        #pragma unroll
        for (int Nt = 0; Nt < 8; ++Nt) {
          floatx4 aa = accP[Nt];
          aa[0]*=s4[0]; aa[1]*=s4[1]; aa[2]*=s4[2]; aa[3]*=s4[3];
          short8 bT = *(const short8*)&Tzj[pbuf][(Nt*16 + co)*40 + gg*8];
          accP[Nt] = __builtin_amdgcn_mfma_f32_16x16x32_bf16(aP, bT, aa, 0, 0, 0);
        }
      } else if (wv >= 2 && tid2 < 120) {
        float sc = scl[hB];
        accB[0]*=sc; accB[1]*=sc; accB[2]*=sc; accB[3]*=sc;
        const int j0 = (t-1)*32;
        const float* vp = vv + (size_t)j0*480 + c0;
        #pragma unroll 4
        for (int jj = 0; jj < 32; ++jj) {
          float p = pl[hB*33 + jj];
          float4 v = *(const float4*)(vp + (size_t)jj*480);
          accB[0] += p*v.x; accB[1] += p*v.y; accB[2] += p*v.z; accB[3] += p*v.w;
        }
      }
    }
    __syncthreads();  // B: logits ready

    if (t < 24 && wv == 0 && lane < 48) {
      const int h = lane >> 2, q = lane & 3;
      float v[8];
      #pragma unroll
      for (int e = 0; e < 8; ++e) v[e] = lL[(q*8 + e)*17 + h];
      float mt = fmaxf(fmaxf(fmaxf(v[0],v[1]),fmaxf(v[2],v[3])),
                       fmaxf(fmaxf(v[4],v[5]),fmaxf(v[6],v[7])));
      mt = fmaxf(mt, __shfl_xor(mt, 1));
      mt = fmaxf(mt, __shfl_xor(mt, 2));
      float mo = smm[h];
      float mn = fmaxf(mo, mt);
      float sc = __expf(mo - mn);
      float ps = 0.f;
      #pragma unroll
      for (int e = 0; e < 8; ++e) {
        float p = __expf(v[e] - mn);
        pl[h*33 + q*8 + e] = p;
        PT[h*40 + q*8 + e] = f2bf(p);
        ps += p;
      }
      ps += __shfl_xor(ps, 1);
      ps += __shfl_xor(ps, 2);
      if (q == 0) { sms[h] = sms[h]*sc + ps; smm[h] = mn; scl[h] = sc; }
    }
    __syncthreads();  // C: softmax published

    if (t < 23) { cur[0]=nxt[0]; cur[1]=nxt[1]; cur[2]=nxt[2]; cur[3]=nxt[3]; }
  }

  // ---- epilogue ----
  if (wv == 0) {
    float* o = C2 + (size_t)i*2112;
    #pragma unroll
    for (int Nt = 0; Nt < 8; ++Nt) {
      #pragma unroll
      for (int r = 0; r < 4; ++r) {
        int h = gg*4 + r;
        if (h < 12) o[(Nt*16 + co)*12 + h] = accP[Nt][r] / sms[h];
      }
    }
  } else if (wv >= 2 && tid2 < 120) {
    float inv = 1.0f / sms[hB];
    #pragma unroll
    for (int e = 0; e < 4; ++e) oacc[c0 + e] = accB[e]*inv;
  }
  __syncthreads();

  if (tid < 96) {
    const int pp = tid / 12, h = tid % 12;
    const float* R = rot + (size_t)i*9;
    const float* T = trans + (size_t)i*3;
    float x0 = oacc[h*40+16+pp*3+0] - T[0];
    float x1 = oacc[h*40+16+pp*3+1] - T[1];
    float x2 = oacc[h*40+16+pp*3+2] - T[2];
    float y0 = R[0]*x0 + R[3]*x1 + R[6]*x2;
    float y1 = R[1]*x0 + R[4]*x1 + R[7]*x2;
    float y2 = R[2]*x0 + R[5]*x1 + R[8]*x2;
    float* o = C2 + (size_t)i*2112;
    o[1728 + pp*36 + h*3 + 0] = y0;
    o[1728 + pp*36 + h*3 + 1] = y1;
    o[1728 + pp*36 + h*3 + 2] = y2;
    o[2016 + pp*12 + h] = sqrtf(y0*y0 + y1*y1 + y2*y2);
  } else if (tid < 192) {
    const int c = tid - 96;
    float* o = C2 + (size_t)i*2112 + 1536;
    o[c]      = oacc[(c%12)*40 + (c/12)];
    o[c+96]   = oacc[((c+96)%12)*40 + ((c+96)/12)];
  }
}

// ---------------- K5: final GEMM 768x2112 @ 2112x384 + bias -------------
__global__ __launch_bounds__(256) void k5_out(
    const float* __restrict__ C2, const float* __restrict__ Wout,
    const float* __restrict__ bout, float* __restrict__ out)
{
  __shared__ float Al[32*68];
  __shared__ float Bl[64*36];
  const int tid = threadIdx.x;
  const int bm = blockIdx.x / 12, bn = blockIdx.x % 12;
  const int tr = tid / 16, tc = tid % 16;
  float acc00=0, acc01=0, acc10=0, acc11=0;
  for (int kc = 0; kc < 33; ++kc) {
    __syncthreads();
    for (int s = tid; s < 512; s += 256) {
      int row = s / 16, kq = s % 16;
      *(float4*)(&Al[row*68 + kq*4]) =
        *(const float4*)(C2 + (size_t)(bm*32+row)*2112 + kc*64 + kq*4);
    }
    for (int s = tid; s < 512; s += 256) {
      int kk = s / 8, cq = s % 8;
      *(float4*)(&Bl[kk*36 + cq*4]) =
        *(const float4*)(Wout + (size_t)(kc*64+kk)*384 + bn*32 + cq*4);
    }
    __syncthreads();
    for (int kk = 0; kk < 64; ++kk) {
      float a0 = Al[(tr*2)*68 + kk], a1 = Al[(tr*2+1)*68 + kk];
      float b0 = Bl[kk*36 + tc*2], b1 = Bl[kk*36 + tc*2 + 1];
      acc00 += a0*b0; acc01 += a0*b1;
      acc10 += a1*b0; acc11 += a1*b1;
    }
  }
  int r0 = bm*32 + tr*2, c0 = bn*32 + tc*2;
  out[(size_t)r0*384 + c0]       = acc00 + bout[c0];
  out[(size_t)r0*384 + c0+1]     = acc01 + bout[c0+1];
  out[(size_t)(r0+1)*384 + c0]   = acc10 + bout[c0];
  out[(size_t)(r0+1)*384 + c0+1] = acc11 + bout[c0+1];
}

extern "C" void kernel_launch(void* const* d_in, const int* in_sizes, int n_in,
                              void* d_out, int out_size, void* d_ws, size_t ws_size,
                              hipStream_t stream)
{
  const float* single = (const float*)d_in[0];
  const float* pair   = (const float*)d_in[1];
  const float* rot    = (const float*)d_in[2];
  const float* trans  = (const float*)d_in[3];
  const float* Wqkv   = (const float*)d_in[4];
  const float* Wb     = (const float*)d_in[5];
  const float* Wqk    = (const float*)d_in[6];
  const float* Wvp    = (const float*)d_in[7];
  const float* gamma  = (const float*)d_in[8];
  const float* Wout   = (const float*)d_in[9];
  const float* bout   = (const float*)d_in[10];

  float* ws   = (float*)d_ws;
  float* raw  = ws;                                  // 768*1152
  float* Qt   = raw + (size_t)768*1152;              // 768*384
  float* vvp  = Qt + (size_t)768*384;                // 768*480
  float* C2   = vvp + (size_t)768*480;               // 768*2112
  ushort_t* Ktb = (ushort_t*)(C2 + (size_t)768*2112); // 768*384 bf16
  float* out  = (float*)d_out;

  k1a_gemm<<<dim3(216), dim3(256), 0, stream>>>(single, Wqkv, Wqk, Wvp, raw);
  k1b_pack<<<dim3(192), dim3(256), 0, stream>>>(raw, rot, trans, gamma, Qt, Ktb, vvp);
  k2m<<<dim3(768), dim3(256), 0, stream>>>(pair, Wb, Qt, Ktb, vvp, rot, trans, C2);
  k5_out<<<dim3(288), dim3(256), 0, stream>>>(C2, Wout, bout, out);
}